// Round 11
// baseline (150.894 us; speedup 1.0000x reference)
//
#include <hip/hip_runtime.h>
#include <hip/hip_bf16.h>
#include <math.h>

#define B_    16
#define T1_   64
#define T2_   64
#define D_    1024
#define PROJ_ 512
#define BM    64
#define QK    256                // k per quarter
#define NQ    4                  // quarters
#define QSTEP 8                  // k-steps (of 32) per quarter
#define QBUF  32768              // one A quarter buffer: 64 * 256 * 2B

typedef __attribute__((ext_vector_type(8))) short bf16x8;
typedef __attribute__((ext_vector_type(4))) float f32x4;
typedef __attribute__((ext_vector_type(4))) unsigned int u32x4;

// RNE fp32->bf16, no NaN path (inputs are finite)
__device__ __forceinline__ unsigned short f2bf(float f) {
  unsigned int u = __builtin_bit_cast(unsigned int, f);
  u += 0x7FFFu + ((u >> 16) & 1u);
  return (unsigned short)(u >> 16);
}

// tanh(a) = 1 - 2/(exp(2a)+1); v_exp_f32 + v_rcp_f32, ~5 instr, |err|~1e-6
__device__ __forceinline__ float fast_tanh(float a) {
  float t = __builtin_amdgcn_exp2f(a * 2.885390081777927f);  // exp(2a)
  return 1.0f - 2.0f * __builtin_amdgcn_rcpf(t + 1.0f);
}

// ---------------------------------------------------------------------------
// Prep: Wt fragment-ordered bf16. 16B chunk index ((t32*32 + n16)*64 + lane)
// holds W[k][n], n = n16*16 + (lane&15), k = t32*32 + (lane>>4)*8 + j.
// ---------------------------------------------------------------------------
__global__ __launch_bounds__(256) void make_bfrag(
    const float* __restrict__ W, unsigned short* __restrict__ wt) {
  __shared__ float tile[32][33];
  const int t  = blockIdx.x;        // k-step 0..31
  const int np = blockIdx.y;        // n-pair 0..15
  const int tx = threadIdx.x & 31;
  const int ty = threadIdx.x >> 5;  // 0..7
#pragma unroll
  for (int i = 0; i < 4; ++i)
    tile[ty + i * 8][tx] =
        W[(size_t)(t * 32 + ty + i * 8) * PROJ_ + np * 32 + tx];
  __syncthreads();
  if (threadIdx.x < 128) {
    const int sub  = threadIdx.x >> 6;   // 0..1
    const int lane = threadIdx.x & 63;
    const int llo = lane & 15, lhi = lane >> 4;
    unsigned short o[8];
#pragma unroll
    for (int j = 0; j < 8; ++j)
      o[j] = f2bf(tile[lhi * 8 + j][sub * 16 + llo]);
    const int n16 = np * 2 + sub;
    *(u32x4*)(wt + ((size_t)(t * 32 + n16) * 64 + lane) * 8) = *(const u32x4*)o;
  }
}

// ---------------------------------------------------------------------------
// Fused: one (b,t1) group of 64 rows per 512-thread block (8 waves).
// scores = v . tanh(x @ W) via bf16 MFMA -> softmax(64) -> out = attn . x
// A processed in 4 K-quarters (64x256 bf16, XOR-swizzled, 2x32KB dbuf):
//   quarter t: ISSUE next quarter's global loads (T14 issue-early), run a
//   barrier-free 8-step KLOOP on buf[t&1], CONVERT+WRITE to buf[t^1] at
//   quarter end (write-late; HBM latency hidden under the kloop), 1 barrier.
// B: register fragments from L2-resident fragment-ordered Wt.
// __launch_bounds__(512,2): reg cap 256 -> NO spill (lost R8/R9 to spill);
// LDS 64KB + ~150 regs -> 1 block/CU; overlap is within-block.
// ---------------------------------------------------------------------------
__global__ __launch_bounds__(512, 2) void fused_kernel(
    const float* __restrict__ x, const unsigned short* __restrict__ wt,
    const float* __restrict__ v, float* __restrict__ out) {
  __shared__ __align__(16) char smem[2 * QBUF];   // A dbuf; epilogue overlays
  float (*sp)[9] = (float(*)[9])smem;             // 2304 B
  float* attn    = (float*)(smem + 2304);         // 256 B
  f32x4* xred    = (f32x4*)(smem + 2560);         // 4 KB

  const int tid  = threadIdx.x;
  const int lane = tid & 63;
  const int wid  = tid >> 6;            // 0..7 = 64-col n-slice
  const int llo  = lane & 15, lhi = lane >> 4;
  const int swz  = (llo & 7) << 4;      // A-read swizzle (row&7 == llo&7)
  const int bt   = blockIdx.x;
  const int m0   = bt * BM;

  f32x4 acc[4][4];
#pragma unroll
  for (int mf = 0; mf < 4; ++mf)
#pragma unroll
    for (int nf = 0; nf < 4; ++nf) acc[mf][nf] = (f32x4){0.f, 0.f, 0.f, 0.f};

  // staging map: unit u (0..3): row = u*16 + (tid>>5), pc = tid&31 (8 floats)
  // global: up0 + u*16*1024 + q*256 ; LDS byte: wbase + u*8192 (write buf)
  const int srow = tid >> 5, spc = tid & 31;
  const float* up0 = x + (size_t)(m0 + srow) * D_ + spc * 8;
  const int wbase = ((srow * 512 + spc * 16)) ^ ((srow & 7) << 4);

  const u32x4* wt4 = (const u32x4*)wt;  // chunk idx (t32*32 + n16)*64 + lane
  const int bbase = (wid * 4) * 64 + lane;

  // B(t32=0) prefetch
  u32x4 rb[4];
#pragma unroll
  for (int nf = 0; nf < 4; ++nf) rb[nf] = wt4[bbase + nf * 64];

#define ISSUE(Q, GA0, GB0, GA1, GB1, GA2, GB2, GA3, GB3)                      \
  GA0 = *(const float4*)(up0 + (Q) * QK);                                     \
  GB0 = *(const float4*)(up0 + (Q) * QK + 4);                                 \
  GA1 = *(const float4*)(up0 + 16384 + (Q) * QK);                             \
  GB1 = *(const float4*)(up0 + 16384 + (Q) * QK + 4);                         \
  GA2 = *(const float4*)(up0 + 32768 + (Q) * QK);                             \
  GB2 = *(const float4*)(up0 + 32768 + (Q) * QK + 4);                         \
  GA3 = *(const float4*)(up0 + 49152 + (Q) * QK);                             \
  GB3 = *(const float4*)(up0 + 49152 + (Q) * QK + 4);

#define WRITE1(BUFW, U, GA, GB)                                               \
  {                                                                           \
    unsigned short o[8] = {f2bf(GA.x), f2bf(GA.y), f2bf(GA.z), f2bf(GA.w),    \
                           f2bf(GB.x), f2bf(GB.y), f2bf(GB.z), f2bf(GB.w)};   \
    *(u32x4*)((BUFW) + wbase + (U) * 8192) = *(const u32x4*)o;                \
  }

  float4 g0a, g0b, g1a, g1b, g2a, g2b, g3a, g3b;

  // ---- prologue: stage quarter 0 into buf0 ----
  ISSUE(0, g0a, g0b, g1a, g1b, g2a, g2b, g3a, g3b)
  WRITE1(smem, 0, g0a, g0b)
  WRITE1(smem, 1, g1a, g1b)
  WRITE1(smem, 2, g2a, g2b)
  WRITE1(smem, 3, g3a, g3b)
  asm volatile("s_waitcnt lgkmcnt(0)" ::: "memory");
  __builtin_amdgcn_s_barrier();

  // ---- quarter loop ----
#pragma unroll
  for (int t = 0; t < NQ; ++t) {
    char* bufr = smem + (t & 1) * QBUF;
    char* bufw = smem + ((t + 1) & 1) * QBUF;
    if (t + 1 < NQ) {                       // issue-early: next quarter
      ISSUE(t + 1, g0a, g0b, g1a, g1b, g2a, g2b, g3a, g3b)
    }
    // barrier-free kloop: 8 steps on bufr (read-only)
#pragma unroll 2
    for (int ks = 0; ks < QSTEP; ++ks) {
      const int t32 = t * QSTEP + ks;
      bf16x8 af0 = *(const bf16x8*)(bufr + ((( 0 + llo) * 512 + ks * 64 + lhi * 16) ^ swz));
      bf16x8 af1 = *(const bf16x8*)(bufr + (((16 + llo) * 512 + ks * 64 + lhi * 16) ^ swz));
      bf16x8 af2 = *(const bf16x8*)(bufr + (((32 + llo) * 512 + ks * 64 + lhi * 16) ^ swz));
      bf16x8 af3 = *(const bf16x8*)(bufr + (((48 + llo) * 512 + ks * 64 + lhi * 16) ^ swz));
      __builtin_amdgcn_s_setprio(1);
#pragma unroll
      for (int nf = 0; nf < 4; ++nf) {
        bf16x8 bfr2 = *(const bf16x8*)&rb[nf];
        acc[0][nf] = __builtin_amdgcn_mfma_f32_16x16x32_bf16(af0, bfr2, acc[0][nf], 0, 0, 0);
        acc[1][nf] = __builtin_amdgcn_mfma_f32_16x16x32_bf16(af1, bfr2, acc[1][nf], 0, 0, 0);
        acc[2][nf] = __builtin_amdgcn_mfma_f32_16x16x32_bf16(af2, bfr2, acc[2][nf], 0, 0, 0);
        acc[3][nf] = __builtin_amdgcn_mfma_f32_16x16x32_bf16(af3, bfr2, acc[3][nf], 0, 0, 0);
        if (t32 + 1 < 32)
          rb[nf] = wt4[(size_t)(t32 + 1) * 2048 + bbase + nf * 64];
      }
      __builtin_amdgcn_s_setprio(0);
    }
    // write-late: convert staged regs into the other buffer, then barrier
    if (t + 1 < NQ) {
      WRITE1(bufw, 0, g0a, g0b)
      WRITE1(bufw, 1, g1a, g1b)
      WRITE1(bufw, 2, g2a, g2b)
      WRITE1(bufw, 3, g3a, g3b)
    }
    asm volatile("s_waitcnt lgkmcnt(0)" ::: "memory");
    __builtin_amdgcn_s_barrier();
  }
#undef ISSUE
#undef WRITE1

  // ---- epilogue 1: tanh + dot(v-slice) + 16-lane reduce -> sp[row][wid] ----
  {
    const float vv0 = v[wid * 64 +  0 + llo];
    const float vv1 = v[wid * 64 + 16 + llo];
    const float vv2 = v[wid * 64 + 32 + llo];
    const float vv3 = v[wid * 64 + 48 + llo];
#pragma unroll
    for (int mf = 0; mf < 4; ++mf) {
      float pr[4] = {0.f, 0.f, 0.f, 0.f};
#pragma unroll
      for (int r = 0; r < 4; ++r) {
        pr[r] += fast_tanh(acc[mf][0][r]) * vv0;
        pr[r] += fast_tanh(acc[mf][1][r]) * vv1;
        pr[r] += fast_tanh(acc[mf][2][r]) * vv2;
        pr[r] += fast_tanh(acc[mf][3][r]) * vv3;
      }
#pragma unroll
      for (int r = 0; r < 4; ++r) {
        float p = pr[r];
        p += __shfl_xor(p, 1, 64);
        p += __shfl_xor(p, 2, 64);
        p += __shfl_xor(p, 4, 64);
        p += __shfl_xor(p, 8, 64);
        if (llo == 0) sp[mf * 16 + lhi * 4 + r][wid] = p;
      }
    }
  }
  __syncthreads();

  // ---- epilogue 2: softmax over the 64 rows (wave 0) ----
  if (tid < BM) {
    float s = 0.f;
#pragma unroll
    for (int w = 0; w < 8; ++w) s += sp[tid][w];
    float mx = s;
#pragma unroll
    for (int mask = 1; mask < 64; mask <<= 1)
      mx = fmaxf(mx, __shfl_xor(mx, mask, 64));
    const float e = __builtin_amdgcn_exp2f((s - mx) * 1.442695040888963f);
    float sum = e;
#pragma unroll
    for (int mask = 1; mask < 64; mask <<= 1)
      sum += __shfl_xor(sum, mask, 64);
    attn[tid] = e * __builtin_amdgcn_rcpf(sum);
  }
  __syncthreads();

  // ---- epilogue 3: out = sum_s attn[s]*x[m0+s][:], 2-way s-split, MLP=4 ----
  const int c4 = tid & 255;
  const int sh = tid >> 8;
  const float* xg = x + ((size_t)m0 + sh * 32) * D_ + c4 * 4;
  f32x4 o0 = {0.f,0.f,0.f,0.f}, o1 = o0, o2 = o0, o3 = o0;
#pragma unroll
  for (int s = 0; s < 32; s += 4) {
    const float w0 = attn[sh * 32 + s + 0];
    const float w1 = attn[sh * 32 + s + 1];
    const float w2 = attn[sh * 32 + s + 2];
    const float w3 = attn[sh * 32 + s + 3];
    const float4 a0 = *(const float4*)(xg + (size_t)(s + 0) * D_);
    const float4 a1 = *(const float4*)(xg + (size_t)(s + 1) * D_);
    const float4 a2 = *(const float4*)(xg + (size_t)(s + 2) * D_);
    const float4 a3 = *(const float4*)(xg + (size_t)(s + 3) * D_);
    o0[0] += w0 * a0.x; o0[1] += w0 * a0.y; o0[2] += w0 * a0.z; o0[3] += w0 * a0.w;
    o1[0] += w1 * a1.x; o1[1] += w1 * a1.y; o1[2] += w1 * a1.z; o1[3] += w1 * a1.w;
    o2[0] += w2 * a2.x; o2[1] += w2 * a2.y; o2[2] += w2 * a2.z; o2[3] += w2 * a2.w;
    o3[0] += w3 * a3.x; o3[1] += w3 * a3.y; o3[2] += w3 * a3.z; o3[3] += w3 * a3.w;
  }
  f32x4 o;
#pragma unroll
  for (int j = 0; j < 4; ++j) o[j] = (o0[j] + o1[j]) + (o2[j] + o3[j]);
  if (sh == 1) xred[c4] = o;
  __syncthreads();
  if (sh == 0) {
    f32x4 o2b = xred[c4];
    float4 res = {o[0] + o2b[0], o[1] + o2b[1], o[2] + o2b[2], o[3] + o2b[3]};
    *(float4*)(out + (size_t)bt * D_ + c4 * 4) = res;
  }
}

extern "C" void kernel_launch(void* const* d_in, const int* in_sizes, int n_in,
                              void* d_out, int out_size, void* d_ws, size_t ws_size,
                              hipStream_t stream) {
  const float* x = (const float*)d_in[0];   // (16,64,64,1024) fp32
  const float* W = (const float*)d_in[1];   // (1024,512) fp32
  const float* v = (const float*)d_in[2];   // (512,) fp32
  float* out = (float*)d_out;               // (16,64,1024) fp32
  unsigned short* Wt = (unsigned short*)d_ws;  // 1 MB fragment-ordered bf16

  make_bfrag<<<dim3(32, PROJ_ / 32), 256, 0, stream>>>(W, Wt);
  fused_kernel<<<B_ * T1_, 512, 0, stream>>>(x, Wt, v, out);
}